// Round 13
// baseline (270.734 us; speedup 1.0000x reference)
//
#include <hip/hip_runtime.h>
#include <math.h>

// ClusterGCN 3-layer inference, MI355X — R13.
// R12 post-mortem: plain stores fixed the R11 WRITE blowup; 270us best.
// R13: clean A/B on gather MLP — unroll-8 neighbor loads (8 uint4 in flight
// per lane) with PLAIN stores (R11 confounded this with nontemporal stores).
// Everything else identical to R12.

constexpr int DK = 128;
constexpr int NBUCK = 256;

typedef __attribute__((ext_vector_type(8))) short bf16x8;
typedef __attribute__((ext_vector_type(4))) float f32x4;

__device__ inline unsigned short f2bf(float f) {
    unsigned int u; __builtin_memcpy(&u, &f, 4);
    unsigned int r = (u + 0x7FFFu + ((u >> 16) & 1u)) >> 16;
    return (unsigned short)r;
}
__device__ inline float blo(unsigned int u) {
    unsigned int t = u << 16; float f; __builtin_memcpy(&f, &t, 4); return f;
}
__device__ inline float bhi(unsigned int u) {
    unsigned int t = u & 0xffff0000u; float f; __builtin_memcpy(&f, &t, 4); return f;
}

// ---------------- merged prep: x->bf16, 3x weight swizzle, zero bhist -------
__device__ void wprep_body(const float* __restrict__ Wout, const float* __restrict__ Wroot,
                           uint4* __restrict__ frag, int dout, int tid) {
    int total = 8 * (dout >> 4) * 64;
    if (tid >= total) return;
    int L = tid & 63;
    int fu = (tid >> 6) % (dout >> 4);
    int t = (tid >> 6) / (dout >> 4);
    int quad = L >> 4, l15 = L & 15;
    int n = fu * 16 + l15;
    unsigned int p[4];
#pragma unroll
    for (int jj = 0; jj < 4; ++jj) {
        int k0 = t * 32 + quad * 8 + jj * 2;
        float v0 = (k0 < 128) ? Wout[k0 * dout + n] : Wroot[(k0 - 128) * dout + n];
        int k1 = k0 + 1;
        float v1 = (k1 < 128) ? Wout[k1 * dout + n] : Wroot[(k1 - 128) * dout + n];
        p[jj] = (unsigned)f2bf(v0) | ((unsigned)f2bf(v1) << 16);
    }
    frag[tid] = make_uint4(p[0], p[1], p[2], p[3]);
}

__global__ void k_prep(const float4* __restrict__ x, uint2* __restrict__ xb,
                       int* __restrict__ bhist, int n4,
                       const float* __restrict__ W1o, const float* __restrict__ W1r, uint4* wf1,
                       const float* __restrict__ W2o, const float* __restrict__ W2r, uint4* wf2,
                       const float* __restrict__ W3o, const float* __restrict__ W3r, uint4* wf3) {
    const int nxblk = (n4 + 255) / 256;
    const int b = blockIdx.x;
    if (b == 0) bhist[threadIdx.x] = 0;
    if (b < nxblk) {
        int i = b * 256 + threadIdx.x;
        if (i >= n4) return;
        float4 v = x[i];
        uint2 o;
        o.x = (unsigned)f2bf(v.x) | ((unsigned)f2bf(v.y) << 16);
        o.y = (unsigned)f2bf(v.z) | ((unsigned)f2bf(v.w) << 16);
        xb[i] = o;
    } else if (b < nxblk + 16) {
        wprep_body(W1o, W1r, wf1, 128, (b - nxblk) * 256 + threadIdx.x);
    } else if (b < nxblk + 32) {
        wprep_body(W2o, W2r, wf2, 128, (b - nxblk - 16) * 256 + threadIdx.x);
    } else {
        wprep_body(W3o, W3r, wf3, 64, (b - nxblk - 32) * 256 + threadIdx.x);
    }
}

// ---------------- CSR build: two-level counting sort ----------------
__global__ void k_bhist(const int* __restrict__ col, int* __restrict__ bhist,
                        int e, int bspan) {
    __shared__ int h[NBUCK];
    h[threadIdx.x] = 0;
    __syncthreads();
    for (int i = blockIdx.x * blockDim.x + threadIdx.x; i < e;
         i += gridDim.x * blockDim.x)
        atomicAdd(&h[col[i] / bspan], 1);
    __syncthreads();
    int v = h[threadIdx.x];
    if (v) atomicAdd(&bhist[threadIdx.x], v);
}

__global__ void k_bscan(const int* __restrict__ bhist, int* __restrict__ boffs,
                        int* __restrict__ bcur, int* __restrict__ offs,
                        int n, int e) {
    __shared__ int wsum[4];
    const int tid = threadIdx.x, lane = tid & 63, wid = tid >> 6;
    int v = bhist[tid];
    int ps = v;
#pragma unroll
    for (int off = 1; off < 64; off <<= 1) {
        int t = __shfl_up(ps, off);
        if (lane >= off) ps += t;
    }
    if (lane == 63) wsum[wid] = ps;
    __syncthreads();
    int wb = 0;
    for (int w = 0; w < wid; ++w) wb += wsum[w];
    int excl = wb + ps - v;
    boffs[tid] = excl;
    bcur[tid] = excl;
    if (tid == 255) boffs[256] = excl + v;
    if (tid == 0) offs[n] = e;
}

__global__ void k_part(const int* __restrict__ row, const int* __restrict__ col,
                       int* __restrict__ bcur, unsigned int* __restrict__ ebuf,
                       int e, int bspan) {
    __shared__ int cnt[NBUCK];
    __shared__ int base[NBUCK];
    const int tid = threadIdx.x;
    const int t0 = blockIdx.x * 4096;
    cnt[tid] = 0;
    __syncthreads();
    int bk[16];
#pragma unroll
    for (int k = 0; k < 16; ++k) {
        int i = t0 + k * 256 + tid;
        int b = -1;
        if (i < e) { b = col[i] / bspan; atomicAdd(&cnt[b], 1); }
        bk[k] = b;
    }
    __syncthreads();
    base[tid] = cnt[tid] ? atomicAdd(&bcur[tid], cnt[tid]) : 0;
    cnt[tid] = 0;
    __syncthreads();
#pragma unroll
    for (int k = 0; k < 16; ++k) {
        int i = t0 + k * 256 + tid;
        if (i < e) {
            int b = bk[k];
            int slot = base[b] + atomicAdd(&cnt[b], 1);
            unsigned int colofs = (unsigned)(col[i] - b * bspan);
            ebuf[slot] = ((unsigned)row[i] & 0xFFFFu) | (colofs << 16);
        }
    }
}

__global__ void k_fillb(const unsigned int* __restrict__ ebuf,
                        const int* __restrict__ boffs, int* __restrict__ offs,
                        float* __restrict__ deginv, int* __restrict__ srow,
                        int n, int bspan) {
    __shared__ int cnt[NBUCK];
    __shared__ int cur[NBUCK];
    __shared__ int wsum[4];
    const int b = blockIdx.x, tid = threadIdx.x;
    const int start = boffs[b], end = boffs[b + 1];
    cnt[tid] = 0;
    __syncthreads();
    for (int i = start + tid; i < end; i += 256)
        atomicAdd(&cnt[ebuf[i] >> 16], 1);
    __syncthreads();
    const int v = cnt[tid];
    const int lane = tid & 63, wid = tid >> 6;
    int ps = v;
#pragma unroll
    for (int off = 1; off < 64; off <<= 1) {
        int t = __shfl_up(ps, off);
        if (lane >= off) ps += t;
    }
    if (lane == 63) wsum[wid] = ps;
    __syncthreads();
    int wb = 0;
    for (int w = 0; w < wid; ++w) wb += wsum[w];
    const int excl = start + wb + ps - v;
    const int node = b * bspan + tid;
    if (tid < bspan && node < n) {
        offs[node] = excl;
        deginv[node] = 1.0f / (float)(v + 1);
    }
    cur[tid] = excl;
    __syncthreads();
    for (int i = start + tid; i < end; i += 256) {
        const unsigned u = ebuf[i];
        const int pos = atomicAdd(&cur[u >> 16], 1);
        srow[pos] = (int)(u & 0xFFFFu);
    }
}

// ---------------- gather, 16 lanes/node, uint4 loads, unroll-8, plain store -
__global__ __launch_bounds__(256, 8)
void k_gather16(const uint4* __restrict__ xb, const int* __restrict__ offs,
                const int* __restrict__ srow, const float* __restrict__ deginv,
                uint4* __restrict__ aggb, int n) {
    const int node = blockIdx.x * 16 + (threadIdx.x >> 4);
    const int lane = threadIdx.x & 15;
    if (node >= n) return;
    const size_t rb = (size_t)node * 16 + lane;
    uint4 sv = xb[rb];
    float a0 = blo(sv.x), a1 = bhi(sv.x), a2 = blo(sv.y), a3 = bhi(sv.y);
    float a4 = blo(sv.z), a5 = bhi(sv.z), a6 = blo(sv.w), a7 = bhi(sv.w);
    const int s = offs[node], e = offs[node + 1];
    int p = s;
    for (; p + 8 <= e; p += 8) {
        uint4 v[8];
#pragma unroll
        for (int j = 0; j < 8; ++j) v[j] = xb[(size_t)srow[p + j] * 16 + lane];
#pragma unroll
        for (int j = 0; j < 8; j += 2) {
            a0 += blo(v[j].x) + blo(v[j + 1].x); a1 += bhi(v[j].x) + bhi(v[j + 1].x);
            a2 += blo(v[j].y) + blo(v[j + 1].y); a3 += bhi(v[j].y) + bhi(v[j + 1].y);
            a4 += blo(v[j].z) + blo(v[j + 1].z); a5 += bhi(v[j].z) + bhi(v[j + 1].z);
            a6 += blo(v[j].w) + blo(v[j + 1].w); a7 += bhi(v[j].w) + bhi(v[j + 1].w);
        }
    }
    for (; p + 2 <= e; p += 2) {
        const uint4 va = xb[(size_t)srow[p] * 16 + lane];
        const uint4 vb = xb[(size_t)srow[p + 1] * 16 + lane];
        a0 += blo(va.x) + blo(vb.x); a1 += bhi(va.x) + bhi(vb.x);
        a2 += blo(va.y) + blo(vb.y); a3 += bhi(va.y) + bhi(vb.y);
        a4 += blo(va.z) + blo(vb.z); a5 += bhi(va.z) + bhi(vb.z);
        a6 += blo(va.w) + blo(vb.w); a7 += bhi(va.w) + bhi(vb.w);
    }
    if (p < e) {
        const uint4 v = xb[(size_t)srow[p] * 16 + lane];
        a0 += blo(v.x); a1 += bhi(v.x); a2 += blo(v.y); a3 += bhi(v.y);
        a4 += blo(v.z); a5 += bhi(v.z); a6 += blo(v.w); a7 += bhi(v.w);
    }
    const float w = deginv[node];
    uint4 o;
    o.x = (unsigned)f2bf(a0 * w) | ((unsigned)f2bf(a1 * w) << 16);
    o.y = (unsigned)f2bf(a2 * w) | ((unsigned)f2bf(a3 * w) << 16);
    o.z = (unsigned)f2bf(a4 * w) | ((unsigned)f2bf(a5 * w) << 16);
    o.w = (unsigned)f2bf(a6 * w) | ((unsigned)f2bf(a7 * w) << 16);
    aggb[rb] = o;
}

// ---------------- MFMA GEMM (layers 1,2): Y = relu([agg|X]@[Wo;Wr]+b) -------
__global__ __launch_bounds__(256, 2)
void k_gemm_mfma(const unsigned short* __restrict__ aggb,
                 const unsigned short* __restrict__ xb,
                 const uint4* __restrict__ wfrag, const float* __restrict__ bvec,
                 unsigned short* __restrict__ y, int n) {
    const int tid = threadIdx.x;
    const int w = tid >> 6, L = tid & 63;
    const int quad = L >> 4, l15 = L & 15;
    const int m0 = blockIdx.x * 64;

    bf16x8 bfr[8][2];
#pragma unroll
    for (int t = 0; t < 8; ++t)
#pragma unroll
        for (int u = 0; u < 2; ++u)
            bfr[t][u] = *(const bf16x8*)&wfrag[(size_t)((t * 8 + (w * 2 + u)) * 64 + L)];

    f32x4 acc[4][2];
#pragma unroll
    for (int mt = 0; mt < 4; ++mt)
#pragma unroll
        for (int u = 0; u < 2; ++u)
            acc[mt][u] = (f32x4){0.f, 0.f, 0.f, 0.f};

    const bf16x8 zf = {0, 0, 0, 0, 0, 0, 0, 0};
#pragma unroll
    for (int t = 0; t < 8; ++t) {
        const unsigned short* Ab = (t < 4) ? aggb : xb;
        const int koff = (t & 3) * 32 + quad * 8;
        bf16x8 af[4];
#pragma unroll
        for (int mt = 0; mt < 4; ++mt) {
            const int r = m0 + mt * 16 + l15;
            af[mt] = (r < n) ? *(const bf16x8*)(Ab + (size_t)r * 128 + koff) : zf;
        }
#pragma unroll
        for (int mt = 0; mt < 4; ++mt)
#pragma unroll
            for (int u = 0; u < 2; ++u)
                acc[mt][u] = __builtin_amdgcn_mfma_f32_16x16x32_bf16(
                    af[mt], bfr[t][u], acc[mt][u], 0, 0, 0);
    }

    float bb[2];
    bb[0] = bvec[w * 32 + l15];
    bb[1] = bvec[w * 32 + 16 + l15];
#pragma unroll
    for (int mt = 0; mt < 4; ++mt)
#pragma unroll
        for (int u = 0; u < 2; ++u)
#pragma unroll
            for (int r4 = 0; r4 < 4; ++r4) {
                const int r = m0 + mt * 16 + quad * 4 + r4;
                if (r < n) {
                    float v = fmaxf(acc[mt][u][r4] + bb[u], 0.f);
                    y[(size_t)r * 128 + w * 32 + u * 16 + l15] = f2bf(v);
                }
            }
}

// ---------------- layer 3 producer: H = X@W3o (bf16), R = X@W3r + b3 (fp32) -
__global__ __launch_bounds__(256, 2)
void k_gemm3hr(const unsigned short* __restrict__ xb,
               const uint4* __restrict__ wfrag, const float* __restrict__ bvec,
               unsigned short* __restrict__ H, float* __restrict__ R, int n) {
    const int tid = threadIdx.x;
    const int w = tid >> 6, L = tid & 63;
    const int quad = L >> 4, l15 = L & 15;
    const int m0 = blockIdx.x * 64;

    bf16x8 bo[4], br[4];
#pragma unroll
    for (int t = 0; t < 4; ++t) {
        bo[t] = *(const bf16x8*)&wfrag[(size_t)((t * 4 + w) * 64 + L)];
        br[t] = *(const bf16x8*)&wfrag[(size_t)(((t + 4) * 4 + w) * 64 + L)];
    }

    f32x4 accH[4], accR[4];
#pragma unroll
    for (int mt = 0; mt < 4; ++mt) {
        accH[mt] = (f32x4){0.f, 0.f, 0.f, 0.f};
        accR[mt] = (f32x4){0.f, 0.f, 0.f, 0.f};
    }

    const bf16x8 zf = {0, 0, 0, 0, 0, 0, 0, 0};
#pragma unroll
    for (int t = 0; t < 4; ++t) {
        const int koff = t * 32 + quad * 8;
        bf16x8 af[4];
#pragma unroll
        for (int mt = 0; mt < 4; ++mt) {
            const int r = m0 + mt * 16 + l15;
            af[mt] = (r < n) ? *(const bf16x8*)(xb + (size_t)r * 128 + koff) : zf;
        }
#pragma unroll
        for (int mt = 0; mt < 4; ++mt) {
            accH[mt] = __builtin_amdgcn_mfma_f32_16x16x32_bf16(af[mt], bo[t], accH[mt], 0, 0, 0);
            accR[mt] = __builtin_amdgcn_mfma_f32_16x16x32_bf16(af[mt], br[t], accR[mt], 0, 0, 0);
        }
    }

    const float bb = bvec[w * 16 + l15];
#pragma unroll
    for (int mt = 0; mt < 4; ++mt)
#pragma unroll
        for (int r4 = 0; r4 < 4; ++r4) {
            const int r = m0 + mt * 16 + quad * 4 + r4;
            if (r < n) {
                H[(size_t)r * 64 + w * 16 + l15] = f2bf(accH[mt][r4]);
                R[(size_t)r * 64 + w * 16 + l15] = accR[mt][r4] + bb;
            }
        }
}

// ---------------- layer 3 fused gather: 16 lanes/node, uint2, unroll-8 ------
__global__ __launch_bounds__(256, 8)
void k_gather3(const uint2* __restrict__ Hb, const float4* __restrict__ R4,
               const int* __restrict__ offs, const int* __restrict__ srow,
               const float* __restrict__ deginv, float4* __restrict__ out, int n) {
    const int node = blockIdx.x * 16 + (threadIdx.x >> 4);
    const int lane = threadIdx.x & 15;
    if (node >= n) return;
    const size_t rb = (size_t)node * 16 + lane;
    uint2 sv = Hb[rb];
    float a0 = blo(sv.x), a1 = bhi(sv.x), a2 = blo(sv.y), a3 = bhi(sv.y);
    const int s = offs[node], e = offs[node + 1];
    int p = s;
    for (; p + 8 <= e; p += 8) {
        uint2 v[8];
#pragma unroll
        for (int j = 0; j < 8; ++j) v[j] = Hb[(size_t)srow[p + j] * 16 + lane];
#pragma unroll
        for (int j = 0; j < 8; j += 2) {
            a0 += blo(v[j].x) + blo(v[j + 1].x); a1 += bhi(v[j].x) + bhi(v[j + 1].x);
            a2 += blo(v[j].y) + blo(v[j + 1].y); a3 += bhi(v[j].y) + bhi(v[j + 1].y);
        }
    }
    for (; p < e; ++p) {
        const uint2 v = Hb[(size_t)srow[p] * 16 + lane];
        a0 += blo(v.x); a1 += bhi(v.x); a2 += blo(v.y); a3 += bhi(v.y);
    }
    const float w = deginv[node];
    const float4 r = R4[rb];
    float v0 = fmaxf(a0 * w + r.x, 0.f);
    float v1 = fmaxf(a1 * w + r.y, 0.f);
    float v2 = fmaxf(a2 * w + r.z, 0.f);
    float v3 = fmaxf(a3 * w + r.w, 0.f);
    float m = fmaxf(fmaxf(v0, v1), fmaxf(v2, v3));
    m = fmaxf(m, __shfl_xor(m, 1));
    m = fmaxf(m, __shfl_xor(m, 2));
    m = fmaxf(m, __shfl_xor(m, 4));
    m = fmaxf(m, __shfl_xor(m, 8));
    float s2 = __expf(v0 - m) + __expf(v1 - m) + __expf(v2 - m) + __expf(v3 - m);
    s2 += __shfl_xor(s2, 1);
    s2 += __shfl_xor(s2, 2);
    s2 += __shfl_xor(s2, 4);
    s2 += __shfl_xor(s2, 8);
    const float lse = m + __logf(s2);
    out[rb] = make_float4(v0 - lse, v1 - lse, v2 - lse, v3 - lse);
}

extern "C" void kernel_launch(void* const* d_in, const int* in_sizes, int n_in,
                              void* d_out, int out_size, void* d_ws, size_t ws_size,
                              hipStream_t stream) {
    const float* x   = (const float*)d_in[0];
    const int*   ei  = (const int*)d_in[1];
    const float* W1o = (const float*)d_in[2];
    const float* b1  = (const float*)d_in[3];
    const float* W1r = (const float*)d_in[4];
    const float* W2o = (const float*)d_in[5];
    const float* b2  = (const float*)d_in[6];
    const float* W2r = (const float*)d_in[7];
    const float* W3o = (const float*)d_in[8];
    const float* b3  = (const float*)d_in[9];
    const float* W3r = (const float*)d_in[10];

    const int N = in_sizes[0] / DK;   // 50000 (row index fits 16 bits)
    const int E = in_sizes[1] / 2;    // 800000
    const int* row = ei;
    const int* col = ei + E;
    const int bspan = (N + NBUCK - 1) / NBUCK;   // 196

    int*   bhist  = (int*)d_ws;                         // 256
    int*   boffs  = bhist + 256;                        // 257 (pad 288)
    int*   bcur   = boffs + 288;                        // 256
    int*   offs   = bcur + 256;                         // N+1
    float* deginv = (float*)(offs + ((N + 64) & ~63));  // N
    int*   srow   = (int*)(deginv + ((N + 63) & ~63));  // E
    unsigned int* ebuf = (unsigned int*)(srow + ((E + 63) & ~63)); // E
    uint4* wf1    = (uint4*)(ebuf + ((E + 63) & ~63));  // 4096 uint4
    uint4* wf2    = wf1 + 4096;                         // 4096
    uint4* wf3    = wf2 + 4096;                         // 2048
    unsigned short* xbuf = (unsigned short*)(wf3 + 2048);   // N*128 bf16
    unsigned short* aggb = xbuf + (size_t)N * 128;          // N*128 (also H)
    unsigned short* Ya   = aggb + (size_t)N * 128;          // N*128 (also R fp32 N*64)
    float* out = (float*)d_out;

    const int n4 = N * 32;
    const int nxblk = (n4 + 255) / 256;
    k_prep<<<nxblk + 40, 256, 0, stream>>>((const float4*)x, (uint2*)xbuf, bhist, n4,
                                           W1o, W1r, wf1, W2o, W2r, wf2, W3o, W3r, wf3);

    k_bhist<<<400, 256, 0, stream>>>(col, bhist, E, bspan);
    k_bscan<<<1, 256, 0, stream>>>(bhist, boffs, bcur, offs, N, E);
    k_part<<<(E + 4095) / 4096, 256, 0, stream>>>(row, col, bcur, ebuf, E, bspan);
    k_fillb<<<NBUCK, 256, 0, stream>>>(ebuf, boffs, offs, deginv, srow, N, bspan);

    const int Gg = (N + 15) / 16;      // gather grids (16 nodes/block)
    const int Gm = (N + 63) / 64;      // gemm grid

    // layer 1: xbuf -> aggb -> Ya
    k_gather16<<<Gg, 256, 0, stream>>>((const uint4*)xbuf, offs, srow, deginv,
                                       (uint4*)aggb, N);
    k_gemm_mfma<<<Gm, 256, 0, stream>>>(aggb, xbuf, wf1, b1, Ya, N);
    // layer 2: Ya -> aggb -> xbuf
    k_gather16<<<Gg, 256, 0, stream>>>((const uint4*)Ya, offs, srow, deginv,
                                       (uint4*)aggb, N);
    k_gemm_mfma<<<Gm, 256, 0, stream>>>(aggb, Ya, wf2, b2, xbuf, N);
    // layer 3: H=xbuf@W3o (->aggb), R=xbuf@W3r+b3 (->Ya fp32), fused gather
    k_gemm3hr<<<Gm, 256, 0, stream>>>(xbuf, wf3, b3, aggb, (float*)Ya, N);
    k_gather3<<<Gg, 256, 0, stream>>>((const uint2*)aggb, (const float4*)Ya,
                                      offs, srow, deginv, (float4*)out, N);
}

// Round 14
// 268.097 us; speedup vs baseline: 1.0098x; 1.0098x over previous
//
#include <hip/hip_runtime.h>
#include <math.h>

// ClusterGCN 3-layer inference, MI355X — R14.
// R13 A/B: gather MLP not the bottleneck (unroll-4 == unroll-8). Gather is
// bound by L2-miss fill (122MB/gather, x ws 12.8MB >> 4MB L2/XCD).
// R14: sort each node's neighbor list into 16 source-row windows (1.05MB of
// x each) inside k_fillb. All gather blocks co-resident -> machine sweeps
// windows roughly in lockstep -> window stays L2-resident -> ~15/16 of
// neighbor reads become L2 hits. Gather kernels byte-identical to R12.

constexpr int DK = 128;
constexpr int NBUCK = 256;

typedef __attribute__((ext_vector_type(8))) short bf16x8;
typedef __attribute__((ext_vector_type(4))) float f32x4;

__device__ inline unsigned short f2bf(float f) {
    unsigned int u; __builtin_memcpy(&u, &f, 4);
    unsigned int r = (u + 0x7FFFu + ((u >> 16) & 1u)) >> 16;
    return (unsigned short)r;
}
__device__ inline float blo(unsigned int u) {
    unsigned int t = u << 16; float f; __builtin_memcpy(&f, &t, 4); return f;
}
__device__ inline float bhi(unsigned int u) {
    unsigned int t = u & 0xffff0000u; float f; __builtin_memcpy(&f, &t, 4); return f;
}

// ---------------- merged prep: x->bf16, 3x weight swizzle, zero bhist -------
__device__ void wprep_body(const float* __restrict__ Wout, const float* __restrict__ Wroot,
                           uint4* __restrict__ frag, int dout, int tid) {
    int total = 8 * (dout >> 4) * 64;
    if (tid >= total) return;
    int L = tid & 63;
    int fu = (tid >> 6) % (dout >> 4);
    int t = (tid >> 6) / (dout >> 4);
    int quad = L >> 4, l15 = L & 15;
    int n = fu * 16 + l15;
    unsigned int p[4];
#pragma unroll
    for (int jj = 0; jj < 4; ++jj) {
        int k0 = t * 32 + quad * 8 + jj * 2;
        float v0 = (k0 < 128) ? Wout[k0 * dout + n] : Wroot[(k0 - 128) * dout + n];
        int k1 = k0 + 1;
        float v1 = (k1 < 128) ? Wout[k1 * dout + n] : Wroot[(k1 - 128) * dout + n];
        p[jj] = (unsigned)f2bf(v0) | ((unsigned)f2bf(v1) << 16);
    }
    frag[tid] = make_uint4(p[0], p[1], p[2], p[3]);
}

__global__ void k_prep(const float4* __restrict__ x, uint2* __restrict__ xb,
                       int* __restrict__ bhist, int n4,
                       const float* __restrict__ W1o, const float* __restrict__ W1r, uint4* wf1,
                       const float* __restrict__ W2o, const float* __restrict__ W2r, uint4* wf2,
                       const float* __restrict__ W3o, const float* __restrict__ W3r, uint4* wf3) {
    const int nxblk = (n4 + 255) / 256;
    const int b = blockIdx.x;
    if (b == 0) bhist[threadIdx.x] = 0;
    if (b < nxblk) {
        int i = b * 256 + threadIdx.x;
        if (i >= n4) return;
        float4 v = x[i];
        uint2 o;
        o.x = (unsigned)f2bf(v.x) | ((unsigned)f2bf(v.y) << 16);
        o.y = (unsigned)f2bf(v.z) | ((unsigned)f2bf(v.w) << 16);
        xb[i] = o;
    } else if (b < nxblk + 16) {
        wprep_body(W1o, W1r, wf1, 128, (b - nxblk) * 256 + threadIdx.x);
    } else if (b < nxblk + 32) {
        wprep_body(W2o, W2r, wf2, 128, (b - nxblk - 16) * 256 + threadIdx.x);
    } else {
        wprep_body(W3o, W3r, wf3, 64, (b - nxblk - 32) * 256 + threadIdx.x);
    }
}

// ---------------- CSR build: two-level counting sort ----------------
__global__ void k_bhist(const int* __restrict__ col, int* __restrict__ bhist,
                        int e, int bspan) {
    __shared__ int h[NBUCK];
    h[threadIdx.x] = 0;
    __syncthreads();
    for (int i = blockIdx.x * blockDim.x + threadIdx.x; i < e;
         i += gridDim.x * blockDim.x)
        atomicAdd(&h[col[i] / bspan], 1);
    __syncthreads();
    int v = h[threadIdx.x];
    if (v) atomicAdd(&bhist[threadIdx.x], v);
}

__global__ void k_bscan(const int* __restrict__ bhist, int* __restrict__ boffs,
                        int* __restrict__ bcur, int* __restrict__ offs,
                        int n, int e) {
    __shared__ int wsum[4];
    const int tid = threadIdx.x, lane = tid & 63, wid = tid >> 6;
    int v = bhist[tid];
    int ps = v;
#pragma unroll
    for (int off = 1; off < 64; off <<= 1) {
        int t = __shfl_up(ps, off);
        if (lane >= off) ps += t;
    }
    if (lane == 63) wsum[wid] = ps;
    __syncthreads();
    int wb = 0;
    for (int w = 0; w < wid; ++w) wb += wsum[w];
    int excl = wb + ps - v;
    boffs[tid] = excl;
    bcur[tid] = excl;
    if (tid == 255) boffs[256] = excl + v;
    if (tid == 0) offs[n] = e;
}

__global__ void k_part(const int* __restrict__ row, const int* __restrict__ col,
                       int* __restrict__ bcur, unsigned int* __restrict__ ebuf,
                       int e, int bspan) {
    __shared__ int cnt[NBUCK];
    __shared__ int base[NBUCK];
    const int tid = threadIdx.x;
    const int t0 = blockIdx.x * 4096;
    cnt[tid] = 0;
    __syncthreads();
    int bk[16];
#pragma unroll
    for (int k = 0; k < 16; ++k) {
        int i = t0 + k * 256 + tid;
        int b = -1;
        if (i < e) { b = col[i] / bspan; atomicAdd(&cnt[b], 1); }
        bk[k] = b;
    }
    __syncthreads();
    base[tid] = cnt[tid] ? atomicAdd(&bcur[tid], cnt[tid]) : 0;
    cnt[tid] = 0;
    __syncthreads();
#pragma unroll
    for (int k = 0; k < 16; ++k) {
        int i = t0 + k * 256 + tid;
        if (i < e) {
            int b = bk[k];
            int slot = base[b] + atomicAdd(&cnt[b], 1);
            unsigned int colofs = (unsigned)(col[i] - b * bspan);
            ebuf[slot] = ((unsigned)row[i] & 0xFFFFu) | (colofs << 16);
        }
    }
}

// Per-bucket fill with (col, row-window) counting sort. Key = colofs*16 + q,
// q = row>>12 (16 windows x 4096 rows). Thread t owns col t's 16 windows in
// the scan, so offs/deginv fall out per-thread. srow ends up sorted by
// window within each node segment -> gather L2 temporal locality.
__global__ void k_fillb(const unsigned int* __restrict__ ebuf,
                        const int* __restrict__ boffs, int* __restrict__ offs,
                        float* __restrict__ deginv, int* __restrict__ srow,
                        int n, int bspan) {
    __shared__ int cnt[4096];
    __shared__ int wsum[4];
    const int b = blockIdx.x, tid = threadIdx.x;
    const int start = boffs[b], end = boffs[b + 1];
    for (int i = tid; i < 4096; i += 256) cnt[i] = 0;
    __syncthreads();
    for (int i = start + tid; i < end; i += 256) {
        const unsigned u = ebuf[i];
        atomicAdd(&cnt[(int)(u >> 16) * 16 + (int)((u & 0xFFFFu) >> 12)], 1);
    }
    __syncthreads();
    int v[16], s = 0;
#pragma unroll
    for (int r = 0; r < 16; ++r) { v[r] = cnt[tid * 16 + r]; s += v[r]; }
    const int lane = tid & 63, wid = tid >> 6;
    int ps = s;
#pragma unroll
    for (int off = 1; off < 64; off <<= 1) {
        int t = __shfl_up(ps, off);
        if (lane >= off) ps += t;
    }
    if (lane == 63) wsum[wid] = ps;
    __syncthreads();
    int wb = 0;
    for (int w = 0; w < wid; ++w) wb += wsum[w];
    int excl = start + wb + ps - s;
    const int node = b * bspan + tid;
    if (tid < bspan && node < n) {
        offs[node] = excl;
        deginv[node] = 1.0f / (float)(s + 1);
    }
#pragma unroll
    for (int r = 0; r < 16; ++r) { int t = v[r]; cnt[tid * 16 + r] = excl; excl += t; }
    __syncthreads();
    for (int i = start + tid; i < end; i += 256) {
        const unsigned u = ebuf[i];
        const int pos = atomicAdd(&cnt[(int)(u >> 16) * 16 + (int)((u & 0xFFFFu) >> 12)], 1);
        srow[pos] = (int)(u & 0xFFFFu);
    }
}

// ---------------- gather, 16 lanes/node, uint4 loads, unroll-4 (R12) --------
__global__ __launch_bounds__(256, 8)
void k_gather16(const uint4* __restrict__ xb, const int* __restrict__ offs,
                const int* __restrict__ srow, const float* __restrict__ deginv,
                uint4* __restrict__ aggb, int n) {
    const int node = blockIdx.x * 16 + (threadIdx.x >> 4);
    const int lane = threadIdx.x & 15;
    if (node >= n) return;
    const size_t rb = (size_t)node * 16 + lane;
    uint4 sv = xb[rb];
    float a0 = blo(sv.x), a1 = bhi(sv.x), a2 = blo(sv.y), a3 = bhi(sv.y);
    float a4 = blo(sv.z), a5 = bhi(sv.z), a6 = blo(sv.w), a7 = bhi(sv.w);
    const int s = offs[node], e = offs[node + 1];
    int p = s;
    for (; p + 4 <= e; p += 4) {
        const int r0 = srow[p], r1 = srow[p + 1], r2 = srow[p + 2], r3 = srow[p + 3];
        const uint4 v0 = xb[(size_t)r0 * 16 + lane];
        const uint4 v1 = xb[(size_t)r1 * 16 + lane];
        const uint4 v2 = xb[(size_t)r2 * 16 + lane];
        const uint4 v3 = xb[(size_t)r3 * 16 + lane];
        a0 += (blo(v0.x) + blo(v1.x)) + (blo(v2.x) + blo(v3.x));
        a1 += (bhi(v0.x) + bhi(v1.x)) + (bhi(v2.x) + bhi(v3.x));
        a2 += (blo(v0.y) + blo(v1.y)) + (blo(v2.y) + blo(v3.y));
        a3 += (bhi(v0.y) + bhi(v1.y)) + (bhi(v2.y) + bhi(v3.y));
        a4 += (blo(v0.z) + blo(v1.z)) + (blo(v2.z) + blo(v3.z));
        a5 += (bhi(v0.z) + bhi(v1.z)) + (bhi(v2.z) + bhi(v3.z));
        a6 += (blo(v0.w) + blo(v1.w)) + (blo(v2.w) + blo(v3.w));
        a7 += (bhi(v0.w) + bhi(v1.w)) + (bhi(v2.w) + bhi(v3.w));
    }
    for (; p < e; ++p) {
        const uint4 v = xb[(size_t)srow[p] * 16 + lane];
        a0 += blo(v.x); a1 += bhi(v.x); a2 += blo(v.y); a3 += bhi(v.y);
        a4 += blo(v.z); a5 += bhi(v.z); a6 += blo(v.w); a7 += bhi(v.w);
    }
    const float w = deginv[node];
    uint4 o;
    o.x = (unsigned)f2bf(a0 * w) | ((unsigned)f2bf(a1 * w) << 16);
    o.y = (unsigned)f2bf(a2 * w) | ((unsigned)f2bf(a3 * w) << 16);
    o.z = (unsigned)f2bf(a4 * w) | ((unsigned)f2bf(a5 * w) << 16);
    o.w = (unsigned)f2bf(a6 * w) | ((unsigned)f2bf(a7 * w) << 16);
    aggb[rb] = o;
}

// ---------------- MFMA GEMM (layers 1,2): Y = relu([agg|X]@[Wo;Wr]+b) -------
__global__ __launch_bounds__(256, 2)
void k_gemm_mfma(const unsigned short* __restrict__ aggb,
                 const unsigned short* __restrict__ xb,
                 const uint4* __restrict__ wfrag, const float* __restrict__ bvec,
                 unsigned short* __restrict__ y, int n) {
    const int tid = threadIdx.x;
    const int w = tid >> 6, L = tid & 63;
    const int quad = L >> 4, l15 = L & 15;
    const int m0 = blockIdx.x * 64;

    bf16x8 bfr[8][2];
#pragma unroll
    for (int t = 0; t < 8; ++t)
#pragma unroll
        for (int u = 0; u < 2; ++u)
            bfr[t][u] = *(const bf16x8*)&wfrag[(size_t)((t * 8 + (w * 2 + u)) * 64 + L)];

    f32x4 acc[4][2];
#pragma unroll
    for (int mt = 0; mt < 4; ++mt)
#pragma unroll
        for (int u = 0; u < 2; ++u)
            acc[mt][u] = (f32x4){0.f, 0.f, 0.f, 0.f};

    const bf16x8 zf = {0, 0, 0, 0, 0, 0, 0, 0};
#pragma unroll
    for (int t = 0; t < 8; ++t) {
        const unsigned short* Ab = (t < 4) ? aggb : xb;
        const int koff = (t & 3) * 32 + quad * 8;
        bf16x8 af[4];
#pragma unroll
        for (int mt = 0; mt < 4; ++mt) {
            const int r = m0 + mt * 16 + l15;
            af[mt] = (r < n) ? *(const bf16x8*)(Ab + (size_t)r * 128 + koff) : zf;
        }
#pragma unroll
        for (int mt = 0; mt < 4; ++mt)
#pragma unroll
            for (int u = 0; u < 2; ++u)
                acc[mt][u] = __builtin_amdgcn_mfma_f32_16x16x32_bf16(
                    af[mt], bfr[t][u], acc[mt][u], 0, 0, 0);
    }

    float bb[2];
    bb[0] = bvec[w * 32 + l15];
    bb[1] = bvec[w * 32 + 16 + l15];
#pragma unroll
    for (int mt = 0; mt < 4; ++mt)
#pragma unroll
        for (int u = 0; u < 2; ++u)
#pragma unroll
            for (int r4 = 0; r4 < 4; ++r4) {
                const int r = m0 + mt * 16 + quad * 4 + r4;
                if (r < n) {
                    float v = fmaxf(acc[mt][u][r4] + bb[u], 0.f);
                    y[(size_t)r * 128 + w * 32 + u * 16 + l15] = f2bf(v);
                }
            }
}

// ---------------- layer 3 producer: H = X@W3o (bf16), R = X@W3r + b3 (fp32) -
__global__ __launch_bounds__(256, 2)
void k_gemm3hr(const unsigned short* __restrict__ xb,
               const uint4* __restrict__ wfrag, const float* __restrict__ bvec,
               unsigned short* __restrict__ H, float* __restrict__ R, int n) {
    const int tid = threadIdx.x;
    const int w = tid >> 6, L = tid & 63;
    const int quad = L >> 4, l15 = L & 15;
    const int m0 = blockIdx.x * 64;

    bf16x8 bo[4], br[4];
#pragma unroll
    for (int t = 0; t < 4; ++t) {
        bo[t] = *(const bf16x8*)&wfrag[(size_t)((t * 4 + w) * 64 + L)];
        br[t] = *(const bf16x8*)&wfrag[(size_t)(((t + 4) * 4 + w) * 64 + L)];
    }

    f32x4 accH[4], accR[4];
#pragma unroll
    for (int mt = 0; mt < 4; ++mt) {
        accH[mt] = (f32x4){0.f, 0.f, 0.f, 0.f};
        accR[mt] = (f32x4){0.f, 0.f, 0.f, 0.f};
    }

    const bf16x8 zf = {0, 0, 0, 0, 0, 0, 0, 0};
#pragma unroll
    for (int t = 0; t < 4; ++t) {
        const int koff = t * 32 + quad * 8;
        bf16x8 af[4];
#pragma unroll
        for (int mt = 0; mt < 4; ++mt) {
            const int r = m0 + mt * 16 + l15;
            af[mt] = (r < n) ? *(const bf16x8*)(xb + (size_t)r * 128 + koff) : zf;
        }
#pragma unroll
        for (int mt = 0; mt < 4; ++mt) {
            accH[mt] = __builtin_amdgcn_mfma_f32_16x16x32_bf16(af[mt], bo[t], accH[mt], 0, 0, 0);
            accR[mt] = __builtin_amdgcn_mfma_f32_16x16x32_bf16(af[mt], br[t], accR[mt], 0, 0, 0);
        }
    }

    const float bb = bvec[w * 16 + l15];
#pragma unroll
    for (int mt = 0; mt < 4; ++mt)
#pragma unroll
        for (int r4 = 0; r4 < 4; ++r4) {
            const int r = m0 + mt * 16 + quad * 4 + r4;
            if (r < n) {
                H[(size_t)r * 64 + w * 16 + l15] = f2bf(accH[mt][r4]);
                R[(size_t)r * 64 + w * 16 + l15] = accR[mt][r4] + bb;
            }
        }
}

// ---------------- layer 3 fused gather: 16 lanes/node, uint2, unroll-4 ------
__global__ __launch_bounds__(256, 8)
void k_gather3(const uint2* __restrict__ Hb, const float4* __restrict__ R4,
               const int* __restrict__ offs, const int* __restrict__ srow,
               const float* __restrict__ deginv, float4* __restrict__ out, int n) {
    const int node = blockIdx.x * 16 + (threadIdx.x >> 4);
    const int lane = threadIdx.x & 15;
    if (node >= n) return;
    const size_t rb = (size_t)node * 16 + lane;
    uint2 sv = Hb[rb];
    float a0 = blo(sv.x), a1 = bhi(sv.x), a2 = blo(sv.y), a3 = bhi(sv.y);
    const int s = offs[node], e = offs[node + 1];
    int p = s;
    for (; p + 4 <= e; p += 4) {
        const int r0 = srow[p], r1 = srow[p + 1], r2 = srow[p + 2], r3 = srow[p + 3];
        const uint2 v0 = Hb[(size_t)r0 * 16 + lane];
        const uint2 v1 = Hb[(size_t)r1 * 16 + lane];
        const uint2 v2 = Hb[(size_t)r2 * 16 + lane];
        const uint2 v3 = Hb[(size_t)r3 * 16 + lane];
        a0 += (blo(v0.x) + blo(v1.x)) + (blo(v2.x) + blo(v3.x));
        a1 += (bhi(v0.x) + bhi(v1.x)) + (bhi(v2.x) + bhi(v3.x));
        a2 += (blo(v0.y) + blo(v1.y)) + (blo(v2.y) + blo(v3.y));
        a3 += (bhi(v0.y) + bhi(v1.y)) + (bhi(v2.y) + bhi(v3.y));
    }
    for (; p < e; ++p) {
        const uint2 v = Hb[(size_t)srow[p] * 16 + lane];
        a0 += blo(v.x); a1 += bhi(v.x); a2 += blo(v.y); a3 += bhi(v.y);
    }
    const float w = deginv[node];
    const float4 r = R4[rb];
    float v0 = fmaxf(a0 * w + r.x, 0.f);
    float v1 = fmaxf(a1 * w + r.y, 0.f);
    float v2 = fmaxf(a2 * w + r.z, 0.f);
    float v3 = fmaxf(a3 * w + r.w, 0.f);
    float m = fmaxf(fmaxf(v0, v1), fmaxf(v2, v3));
    m = fmaxf(m, __shfl_xor(m, 1));
    m = fmaxf(m, __shfl_xor(m, 2));
    m = fmaxf(m, __shfl_xor(m, 4));
    m = fmaxf(m, __shfl_xor(m, 8));
    float s2 = __expf(v0 - m) + __expf(v1 - m) + __expf(v2 - m) + __expf(v3 - m);
    s2 += __shfl_xor(s2, 1);
    s2 += __shfl_xor(s2, 2);
    s2 += __shfl_xor(s2, 4);
    s2 += __shfl_xor(s2, 8);
    const float lse = m + __logf(s2);
    out[rb] = make_float4(v0 - lse, v1 - lse, v2 - lse, v3 - lse);
}

extern "C" void kernel_launch(void* const* d_in, const int* in_sizes, int n_in,
                              void* d_out, int out_size, void* d_ws, size_t ws_size,
                              hipStream_t stream) {
    const float* x   = (const float*)d_in[0];
    const int*   ei  = (const int*)d_in[1];
    const float* W1o = (const float*)d_in[2];
    const float* b1  = (const float*)d_in[3];
    const float* W1r = (const float*)d_in[4];
    const float* W2o = (const float*)d_in[5];
    const float* b2  = (const float*)d_in[6];
    const float* W2r = (const float*)d_in[7];
    const float* W3o = (const float*)d_in[8];
    const float* b3  = (const float*)d_in[9];
    const float* W3r = (const float*)d_in[10];

    const int N = in_sizes[0] / DK;   // 50000 (row index fits 16 bits)
    const int E = in_sizes[1] / 2;    // 800000
    const int* row = ei;
    const int* col = ei + E;
    const int bspan = (N + NBUCK - 1) / NBUCK;   // 196

    int*   bhist  = (int*)d_ws;                         // 256
    int*   boffs  = bhist + 256;                        // 257 (pad 288)
    int*   bcur   = boffs + 288;                        // 256
    int*   offs   = bcur + 256;                         // N+1
    float* deginv = (float*)(offs + ((N + 64) & ~63));  // N
    int*   srow   = (int*)(deginv + ((N + 63) & ~63));  // E
    unsigned int* ebuf = (unsigned int*)(srow + ((E + 63) & ~63)); // E
    uint4* wf1    = (uint4*)(ebuf + ((E + 63) & ~63));  // 4096 uint4
    uint4* wf2    = wf1 + 4096;                         // 4096
    uint4* wf3    = wf2 + 4096;                         // 2048
    unsigned short* xbuf = (unsigned short*)(wf3 + 2048);   // N*128 bf16
    unsigned short* aggb = xbuf + (size_t)N * 128;          // N*128 (also H)
    unsigned short* Ya   = aggb + (size_t)N * 128;          // N*128 (also R fp32 N*64)
    float* out = (float*)d_out;

    const int n4 = N * 32;
    const int nxblk = (n4 + 255) / 256;
    k_prep<<<nxblk + 40, 256, 0, stream>>>((const float4*)x, (uint2*)xbuf, bhist, n4,
                                           W1o, W1r, wf1, W2o, W2r, wf2, W3o, W3r, wf3);

    k_bhist<<<400, 256, 0, stream>>>(col, bhist, E, bspan);
    k_bscan<<<1, 256, 0, stream>>>(bhist, boffs, bcur, offs, N, E);
    k_part<<<(E + 4095) / 4096, 256, 0, stream>>>(row, col, bcur, ebuf, E, bspan);
    k_fillb<<<NBUCK, 256, 0, stream>>>(ebuf, boffs, offs, deginv, srow, N, bspan);

    const int Gg = (N + 15) / 16;      // gather grids (16 nodes/block)
    const int Gm = (N + 63) / 64;      // gemm grid

    // layer 1: xbuf -> aggb -> Ya
    k_gather16<<<Gg, 256, 0, stream>>>((const uint4*)xbuf, offs, srow, deginv,
                                       (uint4*)aggb, N);
    k_gemm_mfma<<<Gm, 256, 0, stream>>>(aggb, xbuf, wf1, b1, Ya, N);
    // layer 2: Ya -> aggb -> xbuf
    k_gather16<<<Gg, 256, 0, stream>>>((const uint4*)Ya, offs, srow, deginv,
                                       (uint4*)aggb, N);
    k_gemm_mfma<<<Gm, 256, 0, stream>>>(aggb, Ya, wf2, b2, xbuf, N);
    // layer 3: H=xbuf@W3o (->aggb), R=xbuf@W3r+b3 (->Ya fp32), fused gather
    k_gemm3hr<<<Gm, 256, 0, stream>>>(xbuf, wf3, b3, aggb, (float*)Ya, N);
    k_gather3<<<Gg, 256, 0, stream>>>((const uint2*)aggb, (const float4*)Ya,
                                      offs, srow, deginv, (float4*)out, N);
}

// Round 15
// 267.382 us; speedup vs baseline: 1.0125x; 1.0027x over previous
//
#include <hip/hip_runtime.h>
#include <math.h>

// ClusterGCN 3-layer inference, MI355X — R15.
// R14: window-sort neutral (avg 1 edge/window — no phase locality); gather is
// at its L2-fill structural bound for a random graph. R15 targets the GEMMs:
// launch_bounds(256,3) caps VGPR at ~168 (need ~130, no spill) forcing
// >=3 blocks/CU instead of the compiler's potential 2. Everything else = R14.

constexpr int DK = 128;
constexpr int NBUCK = 256;

typedef __attribute__((ext_vector_type(8))) short bf16x8;
typedef __attribute__((ext_vector_type(4))) float f32x4;

__device__ inline unsigned short f2bf(float f) {
    unsigned int u; __builtin_memcpy(&u, &f, 4);
    unsigned int r = (u + 0x7FFFu + ((u >> 16) & 1u)) >> 16;
    return (unsigned short)r;
}
__device__ inline float blo(unsigned int u) {
    unsigned int t = u << 16; float f; __builtin_memcpy(&f, &t, 4); return f;
}
__device__ inline float bhi(unsigned int u) {
    unsigned int t = u & 0xffff0000u; float f; __builtin_memcpy(&f, &t, 4); return f;
}

// ---------------- merged prep: x->bf16, 3x weight swizzle, zero bhist -------
__device__ void wprep_body(const float* __restrict__ Wout, const float* __restrict__ Wroot,
                           uint4* __restrict__ frag, int dout, int tid) {
    int total = 8 * (dout >> 4) * 64;
    if (tid >= total) return;
    int L = tid & 63;
    int fu = (tid >> 6) % (dout >> 4);
    int t = (tid >> 6) / (dout >> 4);
    int quad = L >> 4, l15 = L & 15;
    int n = fu * 16 + l15;
    unsigned int p[4];
#pragma unroll
    for (int jj = 0; jj < 4; ++jj) {
        int k0 = t * 32 + quad * 8 + jj * 2;
        float v0 = (k0 < 128) ? Wout[k0 * dout + n] : Wroot[(k0 - 128) * dout + n];
        int k1 = k0 + 1;
        float v1 = (k1 < 128) ? Wout[k1 * dout + n] : Wroot[(k1 - 128) * dout + n];
        p[jj] = (unsigned)f2bf(v0) | ((unsigned)f2bf(v1) << 16);
    }
    frag[tid] = make_uint4(p[0], p[1], p[2], p[3]);
}

__global__ void k_prep(const float4* __restrict__ x, uint2* __restrict__ xb,
                       int* __restrict__ bhist, int n4,
                       const float* __restrict__ W1o, const float* __restrict__ W1r, uint4* wf1,
                       const float* __restrict__ W2o, const float* __restrict__ W2r, uint4* wf2,
                       const float* __restrict__ W3o, const float* __restrict__ W3r, uint4* wf3) {
    const int nxblk = (n4 + 255) / 256;
    const int b = blockIdx.x;
    if (b == 0) bhist[threadIdx.x] = 0;
    if (b < nxblk) {
        int i = b * 256 + threadIdx.x;
        if (i >= n4) return;
        float4 v = x[i];
        uint2 o;
        o.x = (unsigned)f2bf(v.x) | ((unsigned)f2bf(v.y) << 16);
        o.y = (unsigned)f2bf(v.z) | ((unsigned)f2bf(v.w) << 16);
        xb[i] = o;
    } else if (b < nxblk + 16) {
        wprep_body(W1o, W1r, wf1, 128, (b - nxblk) * 256 + threadIdx.x);
    } else if (b < nxblk + 32) {
        wprep_body(W2o, W2r, wf2, 128, (b - nxblk - 16) * 256 + threadIdx.x);
    } else {
        wprep_body(W3o, W3r, wf3, 64, (b - nxblk - 32) * 256 + threadIdx.x);
    }
}

// ---------------- CSR build: two-level counting sort ----------------
__global__ void k_bhist(const int* __restrict__ col, int* __restrict__ bhist,
                        int e, int bspan) {
    __shared__ int h[NBUCK];
    h[threadIdx.x] = 0;
    __syncthreads();
    for (int i = blockIdx.x * blockDim.x + threadIdx.x; i < e;
         i += gridDim.x * blockDim.x)
        atomicAdd(&h[col[i] / bspan], 1);
    __syncthreads();
    int v = h[threadIdx.x];
    if (v) atomicAdd(&bhist[threadIdx.x], v);
}

__global__ void k_bscan(const int* __restrict__ bhist, int* __restrict__ boffs,
                        int* __restrict__ bcur, int* __restrict__ offs,
                        int n, int e) {
    __shared__ int wsum[4];
    const int tid = threadIdx.x, lane = tid & 63, wid = tid >> 6;
    int v = bhist[tid];
    int ps = v;
#pragma unroll
    for (int off = 1; off < 64; off <<= 1) {
        int t = __shfl_up(ps, off);
        if (lane >= off) ps += t;
    }
    if (lane == 63) wsum[wid] = ps;
    __syncthreads();
    int wb = 0;
    for (int w = 0; w < wid; ++w) wb += wsum[w];
    int excl = wb + ps - v;
    boffs[tid] = excl;
    bcur[tid] = excl;
    if (tid == 255) boffs[256] = excl + v;
    if (tid == 0) offs[n] = e;
}

__global__ void k_part(const int* __restrict__ row, const int* __restrict__ col,
                       int* __restrict__ bcur, unsigned int* __restrict__ ebuf,
                       int e, int bspan) {
    __shared__ int cnt[NBUCK];
    __shared__ int base[NBUCK];
    const int tid = threadIdx.x;
    const int t0 = blockIdx.x * 4096;
    cnt[tid] = 0;
    __syncthreads();
    int bk[16];
#pragma unroll
    for (int k = 0; k < 16; ++k) {
        int i = t0 + k * 256 + tid;
        int b = -1;
        if (i < e) { b = col[i] / bspan; atomicAdd(&cnt[b], 1); }
        bk[k] = b;
    }
    __syncthreads();
    base[tid] = cnt[tid] ? atomicAdd(&bcur[tid], cnt[tid]) : 0;
    cnt[tid] = 0;
    __syncthreads();
#pragma unroll
    for (int k = 0; k < 16; ++k) {
        int i = t0 + k * 256 + tid;
        if (i < e) {
            int b = bk[k];
            int slot = base[b] + atomicAdd(&cnt[b], 1);
            unsigned int colofs = (unsigned)(col[i] - b * bspan);
            ebuf[slot] = ((unsigned)row[i] & 0xFFFFu) | (colofs << 16);
        }
    }
}

// Per-bucket fill with (col, row-window) counting sort (R14).
__global__ void k_fillb(const unsigned int* __restrict__ ebuf,
                        const int* __restrict__ boffs, int* __restrict__ offs,
                        float* __restrict__ deginv, int* __restrict__ srow,
                        int n, int bspan) {
    __shared__ int cnt[4096];
    __shared__ int wsum[4];
    const int b = blockIdx.x, tid = threadIdx.x;
    const int start = boffs[b], end = boffs[b + 1];
    for (int i = tid; i < 4096; i += 256) cnt[i] = 0;
    __syncthreads();
    for (int i = start + tid; i < end; i += 256) {
        const unsigned u = ebuf[i];
        atomicAdd(&cnt[(int)(u >> 16) * 16 + (int)((u & 0xFFFFu) >> 12)], 1);
    }
    __syncthreads();
    int v[16], s = 0;
#pragma unroll
    for (int r = 0; r < 16; ++r) { v[r] = cnt[tid * 16 + r]; s += v[r]; }
    const int lane = tid & 63, wid = tid >> 6;
    int ps = s;
#pragma unroll
    for (int off = 1; off < 64; off <<= 1) {
        int t = __shfl_up(ps, off);
        if (lane >= off) ps += t;
    }
    if (lane == 63) wsum[wid] = ps;
    __syncthreads();
    int wb = 0;
    for (int w = 0; w < wid; ++w) wb += wsum[w];
    int excl = start + wb + ps - s;
    const int node = b * bspan + tid;
    if (tid < bspan && node < n) {
        offs[node] = excl;
        deginv[node] = 1.0f / (float)(s + 1);
    }
#pragma unroll
    for (int r = 0; r < 16; ++r) { int t = v[r]; cnt[tid * 16 + r] = excl; excl += t; }
    __syncthreads();
    for (int i = start + tid; i < end; i += 256) {
        const unsigned u = ebuf[i];
        const int pos = atomicAdd(&cnt[(int)(u >> 16) * 16 + (int)((u & 0xFFFFu) >> 12)], 1);
        srow[pos] = (int)(u & 0xFFFFu);
    }
}

// ---------------- gather, 16 lanes/node, uint4 loads, unroll-4 (R12) --------
__global__ __launch_bounds__(256, 8)
void k_gather16(const uint4* __restrict__ xb, const int* __restrict__ offs,
                const int* __restrict__ srow, const float* __restrict__ deginv,
                uint4* __restrict__ aggb, int n) {
    const int node = blockIdx.x * 16 + (threadIdx.x >> 4);
    const int lane = threadIdx.x & 15;
    if (node >= n) return;
    const size_t rb = (size_t)node * 16 + lane;
    uint4 sv = xb[rb];
    float a0 = blo(sv.x), a1 = bhi(sv.x), a2 = blo(sv.y), a3 = bhi(sv.y);
    float a4 = blo(sv.z), a5 = bhi(sv.z), a6 = blo(sv.w), a7 = bhi(sv.w);
    const int s = offs[node], e = offs[node + 1];
    int p = s;
    for (; p + 4 <= e; p += 4) {
        const int r0 = srow[p], r1 = srow[p + 1], r2 = srow[p + 2], r3 = srow[p + 3];
        const uint4 v0 = xb[(size_t)r0 * 16 + lane];
        const uint4 v1 = xb[(size_t)r1 * 16 + lane];
        const uint4 v2 = xb[(size_t)r2 * 16 + lane];
        const uint4 v3 = xb[(size_t)r3 * 16 + lane];
        a0 += (blo(v0.x) + blo(v1.x)) + (blo(v2.x) + blo(v3.x));
        a1 += (bhi(v0.x) + bhi(v1.x)) + (bhi(v2.x) + bhi(v3.x));
        a2 += (blo(v0.y) + blo(v1.y)) + (blo(v2.y) + blo(v3.y));
        a3 += (bhi(v0.y) + bhi(v1.y)) + (bhi(v2.y) + bhi(v3.y));
        a4 += (blo(v0.z) + blo(v1.z)) + (blo(v2.z) + blo(v3.z));
        a5 += (bhi(v0.z) + bhi(v1.z)) + (bhi(v2.z) + bhi(v3.z));
        a6 += (blo(v0.w) + blo(v1.w)) + (blo(v2.w) + blo(v3.w));
        a7 += (bhi(v0.w) + bhi(v1.w)) + (bhi(v2.w) + bhi(v3.w));
    }
    for (; p < e; ++p) {
        const uint4 v = xb[(size_t)srow[p] * 16 + lane];
        a0 += blo(v.x); a1 += bhi(v.x); a2 += blo(v.y); a3 += bhi(v.y);
        a4 += blo(v.z); a5 += bhi(v.z); a6 += blo(v.w); a7 += bhi(v.w);
    }
    const float w = deginv[node];
    uint4 o;
    o.x = (unsigned)f2bf(a0 * w) | ((unsigned)f2bf(a1 * w) << 16);
    o.y = (unsigned)f2bf(a2 * w) | ((unsigned)f2bf(a3 * w) << 16);
    o.z = (unsigned)f2bf(a4 * w) | ((unsigned)f2bf(a5 * w) << 16);
    o.w = (unsigned)f2bf(a6 * w) | ((unsigned)f2bf(a7 * w) << 16);
    aggb[rb] = o;
}

// ---------------- MFMA GEMM (layers 1,2): Y = relu([agg|X]@[Wo;Wr]+b) -------
__global__ __launch_bounds__(256, 3)
void k_gemm_mfma(const unsigned short* __restrict__ aggb,
                 const unsigned short* __restrict__ xb,
                 const uint4* __restrict__ wfrag, const float* __restrict__ bvec,
                 unsigned short* __restrict__ y, int n) {
    const int tid = threadIdx.x;
    const int w = tid >> 6, L = tid & 63;
    const int quad = L >> 4, l15 = L & 15;
    const int m0 = blockIdx.x * 64;

    bf16x8 bfr[8][2];
#pragma unroll
    for (int t = 0; t < 8; ++t)
#pragma unroll
        for (int u = 0; u < 2; ++u)
            bfr[t][u] = *(const bf16x8*)&wfrag[(size_t)((t * 8 + (w * 2 + u)) * 64 + L)];

    f32x4 acc[4][2];
#pragma unroll
    for (int mt = 0; mt < 4; ++mt)
#pragma unroll
        for (int u = 0; u < 2; ++u)
            acc[mt][u] = (f32x4){0.f, 0.f, 0.f, 0.f};

    const bf16x8 zf = {0, 0, 0, 0, 0, 0, 0, 0};
#pragma unroll
    for (int t = 0; t < 8; ++t) {
        const unsigned short* Ab = (t < 4) ? aggb : xb;
        const int koff = (t & 3) * 32 + quad * 8;
        bf16x8 af[4];
#pragma unroll
        for (int mt = 0; mt < 4; ++mt) {
            const int r = m0 + mt * 16 + l15;
            af[mt] = (r < n) ? *(const bf16x8*)(Ab + (size_t)r * 128 + koff) : zf;
        }
#pragma unroll
        for (int mt = 0; mt < 4; ++mt)
#pragma unroll
            for (int u = 0; u < 2; ++u)
                acc[mt][u] = __builtin_amdgcn_mfma_f32_16x16x32_bf16(
                    af[mt], bfr[t][u], acc[mt][u], 0, 0, 0);
    }

    float bb[2];
    bb[0] = bvec[w * 32 + l15];
    bb[1] = bvec[w * 32 + 16 + l15];
#pragma unroll
    for (int mt = 0; mt < 4; ++mt)
#pragma unroll
        for (int u = 0; u < 2; ++u)
#pragma unroll
            for (int r4 = 0; r4 < 4; ++r4) {
                const int r = m0 + mt * 16 + quad * 4 + r4;
                if (r < n) {
                    float v = fmaxf(acc[mt][u][r4] + bb[u], 0.f);
                    y[(size_t)r * 128 + w * 32 + u * 16 + l15] = f2bf(v);
                }
            }
}

// ---------------- layer 3 producer: H = X@W3o (bf16), R = X@W3r + b3 (fp32) -
__global__ __launch_bounds__(256, 3)
void k_gemm3hr(const unsigned short* __restrict__ xb,
               const uint4* __restrict__ wfrag, const float* __restrict__ bvec,
               unsigned short* __restrict__ H, float* __restrict__ R, int n) {
    const int tid = threadIdx.x;
    const int w = tid >> 6, L = tid & 63;
    const int quad = L >> 4, l15 = L & 15;
    const int m0 = blockIdx.x * 64;

    bf16x8 bo[4], br[4];
#pragma unroll
    for (int t = 0; t < 4; ++t) {
        bo[t] = *(const bf16x8*)&wfrag[(size_t)((t * 4 + w) * 64 + L)];
        br[t] = *(const bf16x8*)&wfrag[(size_t)(((t + 4) * 4 + w) * 64 + L)];
    }

    f32x4 accH[4], accR[4];
#pragma unroll
    for (int mt = 0; mt < 4; ++mt) {
        accH[mt] = (f32x4){0.f, 0.f, 0.f, 0.f};
        accR[mt] = (f32x4){0.f, 0.f, 0.f, 0.f};
    }

    const bf16x8 zf = {0, 0, 0, 0, 0, 0, 0, 0};
#pragma unroll
    for (int t = 0; t < 4; ++t) {
        const int koff = t * 32 + quad * 8;
        bf16x8 af[4];
#pragma unroll
        for (int mt = 0; mt < 4; ++mt) {
            const int r = m0 + mt * 16 + l15;
            af[mt] = (r < n) ? *(const bf16x8*)(xb + (size_t)r * 128 + koff) : zf;
        }
#pragma unroll
        for (int mt = 0; mt < 4; ++mt) {
            accH[mt] = __builtin_amdgcn_mfma_f32_16x16x32_bf16(af[mt], bo[t], accH[mt], 0, 0, 0);
            accR[mt] = __builtin_amdgcn_mfma_f32_16x16x32_bf16(af[mt], br[t], accR[mt], 0, 0, 0);
        }
    }

    const float bb = bvec[w * 16 + l15];
#pragma unroll
    for (int mt = 0; mt < 4; ++mt)
#pragma unroll
        for (int r4 = 0; r4 < 4; ++r4) {
            const int r = m0 + mt * 16 + quad * 4 + r4;
            if (r < n) {
                H[(size_t)r * 64 + w * 16 + l15] = f2bf(accH[mt][r4]);
                R[(size_t)r * 64 + w * 16 + l15] = accR[mt][r4] + bb;
            }
        }
}

// ---------------- layer 3 fused gather: 16 lanes/node, uint2, unroll-4 ------
__global__ __launch_bounds__(256, 8)
void k_gather3(const uint2* __restrict__ Hb, const float4* __restrict__ R4,
               const int* __restrict__ offs, const int* __restrict__ srow,
               const float* __restrict__ deginv, float4* __restrict__ out, int n) {
    const int node = blockIdx.x * 16 + (threadIdx.x >> 4);
    const int lane = threadIdx.x & 15;
    if (node >= n) return;
    const size_t rb = (size_t)node * 16 + lane;
    uint2 sv = Hb[rb];
    float a0 = blo(sv.x), a1 = bhi(sv.x), a2 = blo(sv.y), a3 = bhi(sv.y);
    const int s = offs[node], e = offs[node + 1];
    int p = s;
    for (; p + 4 <= e; p += 4) {
        const int r0 = srow[p], r1 = srow[p + 1], r2 = srow[p + 2], r3 = srow[p + 3];
        const uint2 v0 = Hb[(size_t)r0 * 16 + lane];
        const uint2 v1 = Hb[(size_t)r1 * 16 + lane];
        const uint2 v2 = Hb[(size_t)r2 * 16 + lane];
        const uint2 v3 = Hb[(size_t)r3 * 16 + lane];
        a0 += (blo(v0.x) + blo(v1.x)) + (blo(v2.x) + blo(v3.x));
        a1 += (bhi(v0.x) + bhi(v1.x)) + (bhi(v2.x) + bhi(v3.x));
        a2 += (blo(v0.y) + blo(v1.y)) + (blo(v2.y) + blo(v3.y));
        a3 += (bhi(v0.y) + bhi(v1.y)) + (bhi(v2.y) + bhi(v3.y));
    }
    for (; p < e; ++p) {
        const uint2 v = Hb[(size_t)srow[p] * 16 + lane];
        a0 += blo(v.x); a1 += bhi(v.x); a2 += blo(v.y); a3 += bhi(v.y);
    }
    const float w = deginv[node];
    const float4 r = R4[rb];
    float v0 = fmaxf(a0 * w + r.x, 0.f);
    float v1 = fmaxf(a1 * w + r.y, 0.f);
    float v2 = fmaxf(a2 * w + r.z, 0.f);
    float v3 = fmaxf(a3 * w + r.w, 0.f);
    float m = fmaxf(fmaxf(v0, v1), fmaxf(v2, v3));
    m = fmaxf(m, __shfl_xor(m, 1));
    m = fmaxf(m, __shfl_xor(m, 2));
    m = fmaxf(m, __shfl_xor(m, 4));
    m = fmaxf(m, __shfl_xor(m, 8));
    float s2 = __expf(v0 - m) + __expf(v1 - m) + __expf(v2 - m) + __expf(v3 - m);
    s2 += __shfl_xor(s2, 1);
    s2 += __shfl_xor(s2, 2);
    s2 += __shfl_xor(s2, 4);
    s2 += __shfl_xor(s2, 8);
    const float lse = m + __logf(s2);
    out[rb] = make_float4(v0 - lse, v1 - lse, v2 - lse, v3 - lse);
}

extern "C" void kernel_launch(void* const* d_in, const int* in_sizes, int n_in,
                              void* d_out, int out_size, void* d_ws, size_t ws_size,
                              hipStream_t stream) {
    const float* x   = (const float*)d_in[0];
    const int*   ei  = (const int*)d_in[1];
    const float* W1o = (const float*)d_in[2];
    const float* b1  = (const float*)d_in[3];
    const float* W1r = (const float*)d_in[4];
    const float* W2o = (const float*)d_in[5];
    const float* b2  = (const float*)d_in[6];
    const float* W2r = (const float*)d_in[7];
    const float* W3o = (const float*)d_in[8];
    const float* b3  = (const float*)d_in[9];
    const float* W3r = (const float*)d_in[10];

    const int N = in_sizes[0] / DK;   // 50000 (row index fits 16 bits)
    const int E = in_sizes[1] / 2;    // 800000
    const int* row = ei;
    const int* col = ei + E;
    const int bspan = (N + NBUCK - 1) / NBUCK;   // 196

    int*   bhist  = (int*)d_ws;                         // 256
    int*   boffs  = bhist + 256;                        // 257 (pad 288)
    int*   bcur   = boffs + 288;                        // 256
    int*   offs   = bcur + 256;                         // N+1
    float* deginv = (float*)(offs + ((N + 64) & ~63));  // N
    int*   srow   = (int*)(deginv + ((N + 63) & ~63));  // E
    unsigned int* ebuf = (unsigned int*)(srow + ((E + 63) & ~63)); // E
    uint4* wf1    = (uint4*)(ebuf + ((E + 63) & ~63));  // 4096 uint4
    uint4* wf2    = wf1 + 4096;                         // 4096
    uint4* wf3    = wf2 + 4096;                         // 2048
    unsigned short* xbuf = (unsigned short*)(wf3 + 2048);   // N*128 bf16
    unsigned short* aggb = xbuf + (size_t)N * 128;          // N*128 (also H)
    unsigned short* Ya   = aggb + (size_t)N * 128;          // N*128 (also R fp32 N*64)
    float* out = (float*)d_out;

    const int n4 = N * 32;
    const int nxblk = (n4 + 255) / 256;
    k_prep<<<nxblk + 40, 256, 0, stream>>>((const float4*)x, (uint2*)xbuf, bhist, n4,
                                           W1o, W1r, wf1, W2o, W2r, wf2, W3o, W3r, wf3);

    k_bhist<<<400, 256, 0, stream>>>(col, bhist, E, bspan);
    k_bscan<<<1, 256, 0, stream>>>(bhist, boffs, bcur, offs, N, E);
    k_part<<<(E + 4095) / 4096, 256, 0, stream>>>(row, col, bcur, ebuf, E, bspan);
    k_fillb<<<NBUCK, 256, 0, stream>>>(ebuf, boffs, offs, deginv, srow, N, bspan);

    const int Gg = (N + 15) / 16;      // gather grids (16 nodes/block)
    const int Gm = (N + 63) / 64;      // gemm grid

    // layer 1: xbuf -> aggb -> Ya
    k_gather16<<<Gg, 256, 0, stream>>>((const uint4*)xbuf, offs, srow, deginv,
                                       (uint4*)aggb, N);
    k_gemm_mfma<<<Gm, 256, 0, stream>>>(aggb, xbuf, wf1, b1, Ya, N);
    // layer 2: Ya -> aggb -> xbuf
    k_gather16<<<Gg, 256, 0, stream>>>((const uint4*)Ya, offs, srow, deginv,
                                       (uint4*)aggb, N);
    k_gemm_mfma<<<Gm, 256, 0, stream>>>(aggb, Ya, wf2, b2, xbuf, N);
    // layer 3: H=xbuf@W3o (->aggb), R=xbuf@W3r+b3 (->Ya fp32), fused gather
    k_gemm3hr<<<Gm, 256, 0, stream>>>(xbuf, wf3, b3, aggb, (float*)Ya, N);
    k_gather3<<<Gg, 256, 0, stream>>>((const uint2*)aggb, (const float4*)Ya,
                                      offs, srow, deginv, (float4*)out, N);
}